// Round 5
// baseline (438.380 us; speedup 1.0000x reference)
//
#include <hip/hip_runtime.h>
#include <hip/hip_bf16.h>

#define TQ 1024
#define TK 8192
#define DH 64
#define NBH 32
#define QT 64      // q rows per block
#define KT 64      // keys per K-tile
#define NW 4       // waves per block

typedef __attribute__((ext_vector_type(8))) short short8;
typedef __attribute__((ext_vector_type(4))) short short4v;
typedef __attribute__((ext_vector_type(4))) float f32x4;

static __device__ __forceinline__ short f2bf(float f) {
  __hip_bfloat16 h = __float2bfloat16(f);
  return __builtin_bit_cast(short, h);
}

__global__ __launch_bounds__(256, 2)
void attn_fwd(const float* __restrict__ qg,
              const float* __restrict__ kg,
              const float* __restrict__ vg,
              const int* __restrict__ qcs_p,
              float* __restrict__ outg)
{
  // K tile: [key][d] row-major bf16, byte-swizzled ^((key&7)<<4)
  __shared__ __align__(16) short Klds[KT * DH];
  // V tile transposed: [d][key] bf16, byte-swizzled ^((d&7)<<4)
  __shared__ __align__(16) short Vt[DH * KT];
  // per-wave P: [row 0..15][key 0..63] bf16, byte-swizzled ^((row&7)<<4)
  __shared__ __align__(16) short Plds[NW][16 * KT];

  const int tid  = threadIdx.x;
  const int wave = tid >> 6;
  const int lane = tid & 63;
  const int lg   = lane >> 4;   // 0..3
  const int li   = lane & 15;   // 0..15

  const int bid = blockIdx.x;
  const int bh  = bid & (NBH - 1);   // same-head blocks share XCD (bid%8 == bh%8)
  const int qt  = bid >> 5;
  const int qcs = *qcs_p;

  const int q_base = qt * QT;
  const int wrow   = wave * 16;

  const float* qp = qg + ((size_t)bh * TQ + q_base + wrow) * DH;
  const float* kp = kg + (size_t)bh * TK * DH;
  const float* vp = vg + (size_t)bh * TK * DH;

  // ---- Q fragments, pre-scaled by 1/sqrt(64) * log2(e) ----
  const float qscale = 0.125f * 1.44269504088896f;
  short8 qf[2];
  #pragma unroll
  for (int h = 0; h < 2; ++h) {
    const float* src = qp + li * DH + h * 32 + lg * 8;
    float4 a = *(const float4*)(src);
    float4 b = *(const float4*)(src + 4);
    short8 f;
    f[0] = f2bf(a.x * qscale); f[1] = f2bf(a.y * qscale);
    f[2] = f2bf(a.z * qscale); f[3] = f2bf(a.w * qscale);
    f[4] = f2bf(b.x * qscale); f[5] = f2bf(b.y * qscale);
    f[6] = f2bf(b.z * qscale); f[7] = f2bf(b.w * qscale);
    qf[h] = f;
  }

  f32x4 o[4];
  #pragma unroll
  for (int ct = 0; ct < 4; ++ct) o[ct] = (f32x4){0.f, 0.f, 0.f, 0.f};
  float rm[4], rl[4];
  #pragma unroll
  for (int r = 0; r < 4; ++r) { rm[r] = -1e30f; rl[r] = 0.f; }

  const int lim    = qcs + q_base + QT;
  const int n_keys = lim < TK ? lim : TK;
  const int n_tiles = (n_keys + KT - 1) / KT;

  const int t_key = tid >> 4;        // 0..15
  const int t_d   = (tid & 15) * 4;  // 0..60

  for (int tile = 0; tile < n_tiles; ++tile) {
    const int kt0 = tile * KT;

    // ---- stage K (row-major) and V (transposed), fp32 -> bf16 ----
    #pragma unroll
    for (int it = 0; it < 4; ++it) {
      const int key = t_key + it * 16;
      const size_t goff = (size_t)(kt0 + key) * DH + t_d;
      float4 kv = *(const float4*)(kp + goff);
      short4v ks;
      ks[0] = f2bf(kv.x); ks[1] = f2bf(kv.y);
      ks[2] = f2bf(kv.z); ks[3] = f2bf(kv.w);
      int e = (key * DH + t_d) ^ ((key & 7) << 3);   // element swizzle = byte ^ ((key&7)<<4)
      *(short4v*)(&Klds[e]) = ks;

      float4 vv = *(const float4*)(vp + goff);
      short vs0 = f2bf(vv.x), vs1 = f2bf(vv.y), vs2 = f2bf(vv.z), vs3 = f2bf(vv.w);
      int d0 = t_d;
      Vt[((d0 + 0) * KT + key) ^ (((d0 + 0) & 7) << 3)] = vs0;
      Vt[((d0 + 1) * KT + key) ^ (((d0 + 1) & 7) << 3)] = vs1;
      Vt[((d0 + 2) * KT + key) ^ (((d0 + 2) & 7) << 3)] = vs2;
      Vt[((d0 + 3) * KT + key) ^ (((d0 + 3) & 7) << 3)] = vs3;
    }
    __syncthreads();

    // ---- S = Q K^T : 4 tiles of 16 keys, K-dim 64 = 2 MFMAs each ----
    f32x4 s[4];
    #pragma unroll
    for (int t = 0; t < 4; ++t) {
      f32x4 acc = (f32x4){0.f, 0.f, 0.f, 0.f};
      #pragma unroll
      for (int h = 0; h < 2; ++h) {
        int e = ((t * 16 + li) * DH + h * 32 + lg * 8) ^ ((li & 7) << 3);
        short8 kf = *(const short8*)(&Klds[e]);
        acc = __builtin_amdgcn_mfma_f32_16x16x32_bf16(qf[h], kf, acc, 0, 0, 0);
      }
      s[t] = acc;
    }

    // ---- causal mask (only boundary tiles) ----
    if (kt0 + KT - 1 > qcs + q_base + wrow) {
      #pragma unroll
      for (int t = 0; t < 4; ++t) {
        const int keyg = kt0 + t * 16 + li;
        #pragma unroll
        for (int r = 0; r < 4; ++r) {
          const int qpos = qcs + q_base + wrow + lg * 4 + r;
          if (keyg > qpos) s[t][r] = -INFINITY;
        }
      }
    }

    // ---- online softmax (base-2 domain) ----
    float al[4], mn[4];
    #pragma unroll
    for (int r = 0; r < 4; ++r) {
      float tm = fmaxf(fmaxf(s[0][r], s[1][r]), fmaxf(s[2][r], s[3][r]));
      #pragma unroll
      for (int off = 1; off < 16; off <<= 1)
        tm = fmaxf(tm, __shfl_xor(tm, off, 64));
      float m2 = fmaxf(rm[r], tm);       // rm init -1e30 keeps this finite (no NaN)
      al[r] = __builtin_amdgcn_exp2f(rm[r] - m2);
      mn[r] = m2;
      rm[r] = m2;
    }

    float ps[4] = {0.f, 0.f, 0.f, 0.f};
    #pragma unroll
    for (int t = 0; t < 4; ++t) {
      #pragma unroll
      for (int r = 0; r < 4; ++r) {
        float p = __builtin_amdgcn_exp2f(s[t][r] - mn[r]);  // masked: exp2(-inf)=0
        ps[r] += p;
        const int row = lg * 4 + r;
        Plds[wave][(row * KT + t * 16 + li) ^ ((row & 7) << 3)] = f2bf(p);
      }
    }

    #pragma unroll
    for (int r = 0; r < 4; ++r) {
      float sum = ps[r];
      #pragma unroll
      for (int off = 1; off < 16; off <<= 1)
        sum += __shfl_xor(sum, off, 64);
      rl[r] = rl[r] * al[r] + sum;
      #pragma unroll
      for (int ct = 0; ct < 4; ++ct) o[ct][r] *= al[r];
    }

    // ---- O += P V ----
    #pragma unroll
    for (int sk = 0; sk < 2; ++sk) {
      int ep = (li * KT + sk * 32 + lg * 8) ^ ((li & 7) << 3);
      short8 pf = *(const short8*)(&Plds[wave][ep]);
      #pragma unroll
      for (int ct = 0; ct < 4; ++ct) {
        int ev = ((ct * 16 + li) * KT + sk * 32 + lg * 8) ^ ((li & 7) << 3);
        short8 vf = *(const short8*)(&Vt[ev]);
        o[ct] = __builtin_amdgcn_mfma_f32_16x16x32_bf16(pf, vf, o[ct], 0, 0, 0);
      }
    }
    __syncthreads();
  }

  // ---- epilogue: normalize and store ----
  float* op = outg + ((size_t)bh * TQ + q_base + wrow) * DH;
  #pragma unroll
  for (int r = 0; r < 4; ++r) {
    const float inv = rl[r] > 0.f ? 1.0f / rl[r] : 0.f;
    #pragma unroll
    for (int ct = 0; ct < 4; ++ct) {
      op[(lg * 4 + r) * DH + ct * 16 + li] = o[ct][r] * inv;
    }
  }
}

extern "C" void kernel_launch(void* const* d_in, const int* in_sizes, int n_in,
                              void* d_out, int out_size, void* d_ws, size_t ws_size,
                              hipStream_t stream) {
  const float* q   = (const float*)d_in[0];
  const float* k   = (const float*)d_in[1];
  const float* v   = (const float*)d_in[2];
  const int*   qcs = (const int*)d_in[3];
  float* out = (float*)d_out;

  dim3 grid(NBH * (TQ / QT));   // 32 heads * 16 q-tiles = 512 blocks
  dim3 block(256);
  attn_fwd<<<grid, block, 0, stream>>>(q, k, v, qcs, out);
}